// Round 4
// baseline (1067.118 us; speedup 1.0000x reference)
//
#include <hip/hip_runtime.h>

// images: [B=64, C=3, H=512, W=512] f32
// patches: [B, P=4096, C, 8, 8]; patch p = ph*64 + pw
// contrast[b][p] = (max - min + 1e-8) / (max + min) over 192 elems
// top-512 per image (ties -> lower index), zero the rest, output patch layout.
//
// v5 = v4 with K2 folded into K1 via per-image last-finisher:
//   memset: zero 64 per-image counters (256 B, graph-capturable)
//   K1: contrast (pure 201 MB read); block with ticket 63 of its image runs
//       the seeded binary-search threshold inline (overlaps other images' reads)
//   K3: single-pass zero-or-gather NT write (201 MB W + ~24 MB L3-resident R)

#define B_IMG 64
#define NPAT 4096
#define TOPK 512

typedef float f32x4 __attribute__((ext_vector_type(4)));

// key = (contrast_bits << 12) | (4095 - p): 42 bits, unique, larger = better,
// ties broken toward LOWER patch index (matches jax top_k).
__device__ __forceinline__ unsigned long long make_key(unsigned int fb, int p) {
    return ((unsigned long long)fb << 12) | (unsigned)(NPAT - 1 - p);
}

__device__ __forceinline__ unsigned long long shfl_xor_u64(unsigned long long v, int m) {
    unsigned int lo = (unsigned int)v;
    unsigned int hi = (unsigned int)(v >> 32);
    lo = __shfl_xor(lo, m);
    hi = __shfl_xor(hi, m);
    return ((unsigned long long)hi << 32) | lo;
}

// ---- seeded binary-search threshold for image b (verified v2/v4, bit-exact) ----
__device__ __forceinline__ void topk_image(const float* __restrict__ contrast,
                                           unsigned long long* __restrict__ thresh,
                                           int b, int tid) {
    const float4* row4 = (const float4*)(contrast + (size_t)b * NPAT);
    unsigned long long k[16];
    #pragma unroll
    for (int j = 0; j < 4; ++j) {
        const float4 v = row4[tid * 4 + j];
        const int base = tid * 16 + j * 4;
        k[j * 4 + 0] = make_key(__float_as_uint(v.x), base + 0);
        k[j * 4 + 1] = make_key(__float_as_uint(v.y), base + 1);
        k[j * 4 + 2] = make_key(__float_as_uint(v.z), base + 2);
        k[j * 4 + 3] = make_key(__float_as_uint(v.w), base + 3);
    }

    // block-wide min/max seed (values cluster -> ~30 rounds instead of 42)
    unsigned long long mn = k[0], mx = k[0];
    #pragma unroll
    for (int j = 1; j < 16; ++j) {
        mn = (k[j] < mn) ? k[j] : mn;
        mx = (k[j] > mx) ? k[j] : mx;
    }
    #pragma unroll
    for (int off = 32; off > 0; off >>= 1) {
        unsigned long long on = shfl_xor_u64(mn, off);
        unsigned long long ox = shfl_xor_u64(mx, off);
        mn = (on < mn) ? on : mn;
        mx = (ox > mx) ? ox : mx;
    }
    __shared__ unsigned long long smm[8];
    if ((tid & 63) == 0) { smm[tid >> 6] = mn; smm[4 + (tid >> 6)] = mx; }
    __syncthreads();
    unsigned long long lo = smm[0];
    unsigned long long hi = smm[4];
    #pragma unroll
    for (int w = 1; w < 4; ++w) {
        lo = (smm[w] < lo) ? smm[w] : lo;
        hi = (smm[4 + w] > hi) ? smm[4 + w] : hi;
    }
    // invariant: count(>=lo) == 4096 >= 512; count(>=hi) == 1 < 512 (keys unique)

    __shared__ int wsum[2][4];
    int parity = 0;
    while (hi - lo > 1ULL) {
        const unsigned long long mid = lo + ((hi - lo) >> 1);
        int c = 0;
        #pragma unroll
        for (int j = 0; j < 16; ++j) c += (k[j] >= mid) ? 1 : 0;
        #pragma unroll
        for (int off = 32; off > 0; off >>= 1) c += __shfl_xor(c, off);
        if ((tid & 63) == 0) wsum[parity][tid >> 6] = c;
        __syncthreads();
        const int total = wsum[parity][0] + wsum[parity][1]
                        + wsum[parity][2] + wsum[parity][3];
        if (total >= TOPK) lo = mid; else hi = mid;
        parity ^= 1;   // double buffer: no second barrier needed
    }
    // keys unique => count(>= lo) == 512 exactly
    if (tid == 0) thresh[b] = lo;
}

// ---------------- Kernel 1: contrast + last-finisher threshold ----------------
// grid: 4096 blocks = (b, ph); block: 256 threads; 4 threads per patch (pw).
// After storing its row, each block fences and bumps counter[b]; the block that
// draws ticket 63 (image complete) runs topk_image inline. Classic
// threadfence-reduction pattern: release fence + same-object atomic + acquire
// fence -> safe across XCDs, no co-residency assumption, cannot deadlock.
__global__ __launch_bounds__(256) void contrast_kernel(const float* __restrict__ in,
                                                       float* __restrict__ contrast,
                                                       int* __restrict__ counter,
                                                       unsigned long long* __restrict__ thresh) {
    const int blk = blockIdx.x;
    const int b  = blk >> 6;
    const int ph = blk & 63;
    const int tid = threadIdx.x;
    const int pw  = tid >> 2;   // 0..63
    const int sub = tid & 3;    // 0..3

    float mx = -1e30f, mn = 1e30f;
    #pragma unroll
    for (int i = 0; i < 6; ++i) {
        const int r  = sub * 6 + i;      // 0..23
        const int c  = r >> 3;           // 0..2
        const int py = r & 7;            // 0..7
        const size_t base = (((size_t)b * 3 + c) * 512 + (size_t)ph * 8 + py) * 512
                          + (size_t)pw * 8;
        const float4* rp = (const float4*)(in + base);
        float4 a = rp[0];
        float4 d = rp[1];
        mx = fmaxf(mx, fmaxf(fmaxf(a.x, a.y), fmaxf(a.z, a.w)));
        mx = fmaxf(mx, fmaxf(fmaxf(d.x, d.y), fmaxf(d.z, d.w)));
        mn = fminf(mn, fminf(fminf(a.x, a.y), fminf(a.z, a.w)));
        mn = fminf(mn, fminf(fminf(d.x, d.y), fminf(d.z, d.w)));
    }
    mx = fmaxf(mx, __shfl_xor(mx, 1));
    mx = fmaxf(mx, __shfl_xor(mx, 2));
    mn = fminf(mn, __shfl_xor(mn, 1));
    mn = fminf(mn, __shfl_xor(mn, 2));

    if (sub == 0) {
        const float ctr = (mx - mn + 1e-8f) / (mx + mn);  // IEEE f32, matches ref
        contrast[(size_t)b * NPAT + (size_t)ph * 64 + pw] = ctr;
    }

    // ---- last-finisher election ----
    __threadfence();              // release: publish this block's contrast row
    __syncthreads();              // all stores above precede the ticket draw
    __shared__ int ticket;
    if (tid == 0) ticket = atomicAdd(&counter[b], 1);
    __syncthreads();
    if (ticket == 63) {
        __threadfence();          // acquire: see all 64 blocks' contrast rows
        topk_image(contrast, thresh, b, tid);
    }
}

// ---------------- Kernel 3: masked gather/write (verified v1/v4) ----------------
// grid: 4096 blocks = (b, ph); block: 256 threads.
// Output region for a block: 64 patches * 192 floats = 3072 float4, contiguous.
// NT stores: output never re-read; keeps the input L3-resident for the gather.
__global__ __launch_bounds__(256) void write_kernel(const float* __restrict__ in,
                                                    const float* __restrict__ contrast,
                                                    const unsigned long long* __restrict__ thresh,
                                                    f32x4* __restrict__ out) {
    const int blk = blockIdx.x;
    const int b  = blk >> 6;
    const int ph = blk & 63;

    __shared__ int sel[64];
    if (threadIdx.x < 64) {
        const int p = ph * 64 + threadIdx.x;
        const unsigned int fb = __float_as_uint(contrast[(size_t)b * NPAT + p]);
        sel[threadIdx.x] = (make_key(fb, p) >= thresh[b]) ? 1 : 0;
    }
    __syncthreads();

    const f32x4* in4 = (const f32x4*)in;
    const size_t out_base = ((size_t)b * NPAT + (size_t)ph * 64) * 48;  // float4 units

    #pragma unroll
    for (int it = 0; it < 12; ++it) {
        const int idx = it * 256 + threadIdx.x;   // 0..3071
        const int pl  = idx / 48;                 // local patch 0..63
        const int rem = idx - pl * 48;            // 0..47
        f32x4 v = (f32x4){0.f, 0.f, 0.f, 0.f};
        if (sel[pl]) {
            const int c    = rem >> 4;            // 0..2
            const int t    = rem & 15;
            const int py   = t >> 1;              // 0..7
            const int half = t & 1;               // 0..1
            const size_t a = (((size_t)b * 3 + c) * 512 + (size_t)ph * 8 + py) * 128
                           + (size_t)pl * 2 + half;
            v = in4[a];
        }
        __builtin_nontemporal_store(v, &out[out_base + idx]);  // coalesced, nt
    }
}

extern "C" void kernel_launch(void* const* d_in, const int* in_sizes, int n_in,
                              void* d_out, int out_size, void* d_ws, size_t ws_size,
                              hipStream_t stream) {
    const float* in = (const float*)d_in[0];
    float* out = (float*)d_out;

    // ws layout: contrast (1 MB) | thresh (512 B) | counters (256 B)
    float* contrast = (float*)d_ws;
    unsigned long long* thresh =
        (unsigned long long*)((char*)d_ws + (size_t)B_IMG * NPAT * sizeof(float));
    int* counter = (int*)((char*)thresh + B_IMG * sizeof(unsigned long long));

    // counters live in poisoned workspace: zero them each launch (stream-ordered,
    // graph-capturable; same primitive the harness reset uses)
    hipMemsetAsync(counter, 0, B_IMG * sizeof(int), stream);

    contrast_kernel<<<B_IMG * 64, 256, 0, stream>>>(in, contrast, counter, thresh);
    write_kernel<<<B_IMG * 64, 256, 0, stream>>>(in, contrast, thresh, (f32x4*)out);
}

// Round 5
// 353.699 us; speedup vs baseline: 3.0170x; 3.0170x over previous
//
#include <hip/hip_runtime.h>

// images: [B=64, C=3, H=512, W=512] f32
// patches: [B, P=4096, C, 8, 8]; patch p = ph*64 + pw
// contrast[b][p] = (max - min + 1e-8) / (max + min) over 192 elems
// top-512 per image (ties -> lower index), zero the rest, output patch layout.
//
// v6 = exact revert to verified v4 (354.1 us, absmax 0):
//   K1: contrast (pure 201 MB read)
//   K2: per-image threshold, min/max-seeded binary search (~30 rounds, 1 barrier/round)
//   K3: single-pass zero-or-gather NT write (201 MB W + ~24 MB L3-resident R)
// Rejected by measurement: R/W-mixed fusion (v2, +19us), cooperative grid sync
// (v3, deadlock), per-block threadfence last-finisher (v5, +713us — device-scope
// fences serialize on L2 writeback at 4096-block scale).

#define B_IMG 64
#define NPAT 4096
#define TOPK 512

typedef float f32x4 __attribute__((ext_vector_type(4)));

// key = (contrast_bits << 12) | (4095 - p): 42 bits, unique, larger = better,
// ties broken toward LOWER patch index (matches jax top_k).
__device__ __forceinline__ unsigned long long make_key(unsigned int fb, int p) {
    return ((unsigned long long)fb << 12) | (unsigned)(NPAT - 1 - p);
}

__device__ __forceinline__ unsigned long long shfl_xor_u64(unsigned long long v, int m) {
    unsigned int lo = (unsigned int)v;
    unsigned int hi = (unsigned int)(v >> 32);
    lo = __shfl_xor(lo, m);
    hi = __shfl_xor(hi, m);
    return ((unsigned long long)hi << 32) | lo;
}

// ---------------- Kernel 1: per-patch contrast ----------------
// grid: 4096 blocks = (b, ph); block: 256 threads; 4 threads per patch (pw).
__global__ __launch_bounds__(256) void contrast_kernel(const float* __restrict__ in,
                                                       float* __restrict__ contrast) {
    const int blk = blockIdx.x;
    const int b  = blk >> 6;
    const int ph = blk & 63;
    const int tid = threadIdx.x;
    const int pw  = tid >> 2;   // 0..63
    const int sub = tid & 3;    // 0..3

    float mx = -1e30f, mn = 1e30f;
    #pragma unroll
    for (int i = 0; i < 6; ++i) {
        const int r  = sub * 6 + i;      // 0..23
        const int c  = r >> 3;           // 0..2
        const int py = r & 7;            // 0..7
        const size_t base = (((size_t)b * 3 + c) * 512 + (size_t)ph * 8 + py) * 512
                          + (size_t)pw * 8;
        const float4* rp = (const float4*)(in + base);
        float4 a = rp[0];
        float4 d = rp[1];
        mx = fmaxf(mx, fmaxf(fmaxf(a.x, a.y), fmaxf(a.z, a.w)));
        mx = fmaxf(mx, fmaxf(fmaxf(d.x, d.y), fmaxf(d.z, d.w)));
        mn = fminf(mn, fminf(fminf(a.x, a.y), fminf(a.z, a.w)));
        mn = fminf(mn, fminf(fminf(d.x, d.y), fminf(d.z, d.w)));
    }
    mx = fmaxf(mx, __shfl_xor(mx, 1));
    mx = fmaxf(mx, __shfl_xor(mx, 2));
    mn = fminf(mn, __shfl_xor(mn, 1));
    mn = fminf(mn, __shfl_xor(mn, 2));

    if (sub == 0) {
        const float ctr = (mx - mn + 1e-8f) / (mx + mn);  // IEEE f32, matches ref
        contrast[(size_t)b * NPAT + (size_t)ph * 64 + pw] = ctr;
    }
}

// ---------------- Kernel 2: seeded binary-search threshold ----------------
// One block per image; 16 keys/thread in registers. Search seeded with block
// min/max (values cluster -> ~30 rounds), one barrier per round via
// double-buffered cross-wave sums. Keys unique => exact count==512 at lo.
__global__ __launch_bounds__(256) void topk_kernel(const float* __restrict__ contrast,
                                                   unsigned long long* __restrict__ thresh) {
    const int b   = blockIdx.x;
    const int tid = threadIdx.x;
    const float4* row4 = (const float4*)(contrast + (size_t)b * NPAT);

    unsigned long long k[16];
    #pragma unroll
    for (int j = 0; j < 4; ++j) {
        const float4 v = row4[tid * 4 + j];
        const int base = tid * 16 + j * 4;
        k[j * 4 + 0] = make_key(__float_as_uint(v.x), base + 0);
        k[j * 4 + 1] = make_key(__float_as_uint(v.y), base + 1);
        k[j * 4 + 2] = make_key(__float_as_uint(v.z), base + 2);
        k[j * 4 + 3] = make_key(__float_as_uint(v.w), base + 3);
    }

    // block-wide min/max seed
    unsigned long long mn = k[0], mx = k[0];
    #pragma unroll
    for (int j = 1; j < 16; ++j) {
        mn = (k[j] < mn) ? k[j] : mn;
        mx = (k[j] > mx) ? k[j] : mx;
    }
    #pragma unroll
    for (int off = 32; off > 0; off >>= 1) {
        unsigned long long on = shfl_xor_u64(mn, off);
        unsigned long long ox = shfl_xor_u64(mx, off);
        mn = (on < mn) ? on : mn;
        mx = (ox > mx) ? ox : mx;
    }
    __shared__ unsigned long long smm[8];
    if ((tid & 63) == 0) { smm[tid >> 6] = mn; smm[4 + (tid >> 6)] = mx; }
    __syncthreads();
    unsigned long long lo = smm[0];
    unsigned long long hi = smm[4];
    #pragma unroll
    for (int w = 1; w < 4; ++w) {
        lo = (smm[w] < lo) ? smm[w] : lo;
        hi = (smm[4 + w] > hi) ? smm[4 + w] : hi;
    }
    // invariant: count(>=lo) == 4096 >= 512; count(>=hi) == 1 < 512 (keys unique)

    __shared__ int wsum[2][4];
    int parity = 0;
    while (hi - lo > 1ULL) {
        const unsigned long long mid = lo + ((hi - lo) >> 1);
        int c = 0;
        #pragma unroll
        for (int j = 0; j < 16; ++j) c += (k[j] >= mid) ? 1 : 0;
        #pragma unroll
        for (int off = 32; off > 0; off >>= 1) c += __shfl_xor(c, off);
        if ((tid & 63) == 0) wsum[parity][tid >> 6] = c;
        __syncthreads();
        const int total = wsum[parity][0] + wsum[parity][1]
                        + wsum[parity][2] + wsum[parity][3];
        if (total >= TOPK) lo = mid; else hi = mid;
        parity ^= 1;   // double buffer: no second barrier needed
    }
    // termination: hi == lo+1, count(>=lo) >= 512 > count(>=lo+1)
    // unique keys => count(>=lo) == 512 exactly
    if (tid == 0) thresh[b] = lo;
}

// ---------------- Kernel 3: masked gather/write ----------------
// grid: 4096 blocks = (b, ph); block: 256 threads.
// Output region for a block: 64 patches * 192 floats = 3072 float4, contiguous.
// NT stores: output never re-read; keeps the input L3-resident for the gather.
__global__ __launch_bounds__(256) void write_kernel(const float* __restrict__ in,
                                                    const float* __restrict__ contrast,
                                                    const unsigned long long* __restrict__ thresh,
                                                    f32x4* __restrict__ out) {
    const int blk = blockIdx.x;
    const int b  = blk >> 6;
    const int ph = blk & 63;

    __shared__ int sel[64];
    if (threadIdx.x < 64) {
        const int p = ph * 64 + threadIdx.x;
        const unsigned int fb = __float_as_uint(contrast[(size_t)b * NPAT + p]);
        sel[threadIdx.x] = (make_key(fb, p) >= thresh[b]) ? 1 : 0;
    }
    __syncthreads();

    const f32x4* in4 = (const f32x4*)in;
    const size_t out_base = ((size_t)b * NPAT + (size_t)ph * 64) * 48;  // float4 units

    #pragma unroll
    for (int it = 0; it < 12; ++it) {
        const int idx = it * 256 + threadIdx.x;   // 0..3071
        const int pl  = idx / 48;                 // local patch 0..63
        const int rem = idx - pl * 48;            // 0..47
        f32x4 v = (f32x4){0.f, 0.f, 0.f, 0.f};
        if (sel[pl]) {
            const int c    = rem >> 4;            // 0..2
            const int t    = rem & 15;
            const int py   = t >> 1;              // 0..7
            const int half = t & 1;               // 0..1
            const size_t a = (((size_t)b * 3 + c) * 512 + (size_t)ph * 8 + py) * 128
                           + (size_t)pl * 2 + half;
            v = in4[a];
        }
        __builtin_nontemporal_store(v, &out[out_base + idx]);  // coalesced, nt
    }
}

extern "C" void kernel_launch(void* const* d_in, const int* in_sizes, int n_in,
                              void* d_out, int out_size, void* d_ws, size_t ws_size,
                              hipStream_t stream) {
    const float* in = (const float*)d_in[0];
    float* out = (float*)d_out;

    float* contrast = (float*)d_ws;                                   // 1 MB
    unsigned long long* thresh =
        (unsigned long long*)((char*)d_ws + (size_t)B_IMG * NPAT * sizeof(float));

    contrast_kernel<<<B_IMG * 64, 256, 0, stream>>>(in, contrast);
    topk_kernel<<<B_IMG, 256, 0, stream>>>(contrast, thresh);
    write_kernel<<<B_IMG * 64, 256, 0, stream>>>(in, contrast, thresh, (f32x4*)out);
}